// Round 1
// baseline (106.448 us; speedup 1.0000x reference)
//
#include <hip/hip_runtime.h>

#define HH 2048
#define WW 2048
#define NB 1024
#define TW 512  // tile width  (4 tiles/row)  -> 2 KB contiguous row span per tile
#define TH 8    // tile height (256 tile rows)
// 256 threads/block; thread owns a 4x4 pixel patch: qx = tid&127 (x-quad),
// ry = tid>>7 (row group, 0..1), rows py0..py0+3. A wave's 64 lanes cover
// 256 px of ONE row -> each store instruction writes 1 KB contiguous; the
// wave pair covers the full 2 KB tile row. 4x longer HBM write spans than
// the previous 128x32 tiling (512 B chunks at 8 KB stride).

__global__ __launch_bounds__(256, 4) void paint_kernel(const float4* __restrict__ boxes,
                                                       float* __restrict__ out) {
    __shared__ unsigned long long imaskS[4][4];  // [chunk][wave]
    __shared__ unsigned long long fmaskS[4][4];
    __shared__ uint2 clist[NB];  // packed coords of pruned candidates (idx > lastFull)
    __shared__ short cidxS[NB];

    const int tid  = threadIdx.x;
    const int lane = tid & 63;
    const int wid  = tid >> 6;
    const int tileX = blockIdx.x * TW;
    const int tileY = blockIdx.y * TH;

    // ---- pass 1: load (hoisted, pipelined) + convert + ballot ----
    float4 bxr[4];
    #pragma unroll
    for (int c = 0; c < 4; ++c) bxr[c] = boxes[c * 256 + tid];

    int ry1[4], rx1[4], ry2[4], rx2[4];
    bool rint[4];
    #pragma unroll
    for (int c = 0; c < 4; ++c) {
        float4 bx = bxr[c];
        int y1 = max(0, (int)(bx.x * (float)HH));   // trunc-toward-zero == astype(int32)
        int x1 = max(0, (int)(bx.y * (float)WW));
        int y2 = min(HH, (int)(bx.z * (float)HH));
        int x2 = min(WW, (int)(bx.w * (float)WW));
        ry1[c] = y1; rx1[c] = x1; ry2[c] = y2; rx2[c] = x2;
        bool valid = (y1 < y2) && (x1 < x2);
        bool inter = valid && (y1 < tileY + TH) && (y2 > tileY) &&
                     (x1 < tileX + TW) && (x2 > tileX);
        bool full  = (y1 <= tileY) && (y2 >= tileY + TH) &&
                     (x1 <= tileX) && (x2 >= tileX + TW);
        rint[c] = inter;
        unsigned long long mi = __ballot(inter);
        unsigned long long mf = __ballot(full);
        if (lane == 0) { imaskS[c][wid] = mi; fmaskS[c][wid] = mf; }
    }
    __syncthreads();  // barrier 1

    // ---- lastFull: highest-index box fully covering the tile (block-uniform) ----
    int lastFull = -1;
    #pragma unroll
    for (int c = 3; c >= 0; --c)
        #pragma unroll
        for (int w = 3; w >= 0; --w)
            if (lastFull < 0) {
                unsigned long long m = fmaskS[c][w];
                if (m) lastFull = c * 256 + w * 64 + 63 - __clzll(m);
            }

    // ---- prune masks to idx > lastFull; compute compaction offsets ----
    int cnt_all = 0;
    int myoff[4];
    #pragma unroll
    for (int c = 0; c < 4; ++c) {
        #pragma unroll
        for (int w = 0; w < 4; ++w) {
            unsigned long long m = imaskS[c][w];
            int d = lastFull - (c * 256 + w * 64);
            if (d >= 63) m = 0;
            else if (d >= 0) m &= (~0ull) << (d + 1);
            if (w == wid)
                myoff[c] = cnt_all + __popcll(m & ((1ull << lane) - 1ull));
            cnt_all += __popcll(m);
        }
    }

    // ---- sparse compaction writes (coords still in registers) ----
    #pragma unroll
    for (int c = 0; c < 4; ++c) {
        int b = c * 256 + tid;
        if (rint[c] && b > lastFull) {
            clist[myoff[c]] = make_uint2(((unsigned)ry1[c] << 16) | (unsigned)rx1[c],
                                         ((unsigned)ry2[c] << 16) | (unsigned)rx2[c]);
            cidxS[myoff[c]] = (short)b;
        }
    }
    // pad list to a multiple of 4 with empty boxes (y1==y2==0 -> never covers)
    const int cnt4 = (cnt_all + 3) & ~3;
    if (tid < cnt4 - cnt_all) {
        clist[cnt_all + tid] = make_uint2(0u, 0u);
        cidxS[cnt_all + tid] = 0;
    }
    __syncthreads();  // barrier 2

    const int qx  = tid & 127;
    const int px0 = tileX + qx * 4;
    const int ry  = tid >> 7;
    const int py0 = tileY + ry * 4;

    if (cnt_all == 0) {
        // ---- uniform fast path: whole tile = lastFull box (or zeros) ----
        float4 bv = make_float4(0.f, 0.f, 0.f, 0.f);
        float on = 0.f;
        if (lastFull >= 0) { bv = boxes[lastFull]; on = 1.f; }
        float vals[5] = {on, bv.x, bv.y, bv.z, bv.w};
        #pragma unroll
        for (int ch = 0; ch < 5; ++ch) {
            float4 v = make_float4(vals[ch], vals[ch], vals[ch], vals[ch]);
            size_t base = (size_t)ch * (HH * WW);
            #pragma unroll
            for (int s = 0; s < 4; ++s)
                *(float4*)(out + base + (size_t)(py0 + s) * WW + px0) = v;
        }
    } else {
        // ---- per-pixel ownership: ascending overwrite, 4 candidates/iter ----
        int fnd[4][4];
        #pragma unroll
        for (int s = 0; s < 4; ++s)
            #pragma unroll
            for (int k = 0; k < 4; ++k) fnd[s][k] = lastFull;

        for (int j = 0; j < cnt4; j += 4) {
            uint2 pc[4];
            int bidx[4];
            #pragma unroll
            for (int u = 0; u < 4; ++u) {   // 4 independent LDS reads, pipelined
                pc[u] = clist[j + u];
                bidx[u] = cidxS[j + u];
            }
            #pragma unroll
            for (int u = 0; u < 4; ++u) {
                int by1 = (int)(pc[u].x >> 16), bx1 = (int)(pc[u].x & 0xffffu);
                int by2 = (int)(pc[u].y >> 16), bx2 = (int)(pc[u].y & 0xffffu);
                #pragma unroll
                for (int s = 0; s < 4; ++s) {
                    int py = py0 + s;
                    bool yin = (py >= by1) && (py < by2);
                    #pragma unroll
                    for (int k = 0; k < 4; ++k) {
                        int px = px0 + k;
                        if (yin && px >= bx1 && px < bx2) fnd[s][k] = bidx[u];
                    }
                }
            }
        }
        #pragma unroll
        for (int s = 0; s < 4; ++s) {
            float4 v[5];
            #pragma unroll
            for (int k = 0; k < 4; ++k) {
                int f = fnd[s][k];
                float4 bv = (f >= 0) ? boxes[f] : make_float4(0.f, 0.f, 0.f, 0.f);
                float on = (f >= 0) ? 1.f : 0.f;
                ((float*)&v[0])[k] = on;
                ((float*)&v[1])[k] = bv.x;
                ((float*)&v[2])[k] = bv.y;
                ((float*)&v[3])[k] = bv.z;
                ((float*)&v[4])[k] = bv.w;
            }
            size_t pb = (size_t)(py0 + s) * WW + px0;
            #pragma unroll
            for (int ch = 0; ch < 5; ++ch)
                *(float4*)(out + (size_t)ch * (HH * WW) + pb) = v[ch];
        }
    }
}

extern "C" void kernel_launch(void* const* d_in, const int* in_sizes, int n_in,
                              void* d_out, int out_size, void* d_ws, size_t ws_size,
                              hipStream_t stream) {
    const float4* boxes = (const float4*)d_in[0];
    float* out = (float*)d_out;
    dim3 grid(WW / TW, HH / TH);  // 4 x 256 = 1024 blocks
    dim3 block(256);
    paint_kernel<<<grid, block, 0, stream>>>(boxes, out);
}

// Round 2
// 102.150 us; speedup vs baseline: 1.0421x; 1.0421x over previous
//
#include <hip/hip_runtime.h>

#define HH 2048
#define WW 2048
#define NB 1024
#define NT 512      // threads/block = 8 waves; one wave per image row of the band
#define BANDH 8     // rows per block: block = 2048 x 8 band
#define NSTRIP 16   // 16 strips of 128 px: pruning granularity stays fine
#define SW 128
#define CAP 64      // per-strip candidate capacity (typ. <= ~15; fallback if exceeded)

// Block = full-width 2048x8 band -> write phase is channel-outer: each wave
// emits 5 sequential 8KB contiguous runs (fill-like stream shape), vs the old
// 128x32 tiling's 20 interleaved 512B-chunk streams per wave. Pruning is per
// 128x8 strip (BETTER than 128x32: y-full-cover easier), so candidate lists
// stay tiny. Prologue (1024-box scan) runs once per CU instead of 4x.

__global__ __launch_bounds__(NT, 2) void paint_kernel(const float4* __restrict__ boxes,
                                                      float* __restrict__ out) {
    __shared__ uint2 coordS[NB];                       // packed pixel coords, all boxes
    __shared__ unsigned long long fmS[NSTRIP][2][8];   // full-cover ballots [strip][chunk][wave]
    __shared__ unsigned long long imS[NSTRIP][2][8];   // intersect ballots
    __shared__ uint2 clistS[NSTRIP][CAP];              // compacted candidate coords
    __shared__ short cidxS[NSTRIP][CAP];               // candidate box indices
    __shared__ int lastFullS[NSTRIP];
    __shared__ int cntS[NSTRIP];                       // -1 = overflow -> fallback scan

    const int tid  = threadIdx.x;
    const int lane = tid & 63;
    const int wid  = tid >> 6;
    // XCD-contiguous bands: block B -> band (B%8)*32 + B/8, so XCD i owns rows
    // [i*256, (i+1)*256) and its L2 eviction stream is one contiguous region.
    const int band  = ((blockIdx.x & 7) << 5) | (blockIdx.x >> 3);
    const int tileY = band * BANDH;

    // ---- prologue: load boxes, convert, per-strip ballot masks ----
    unsigned im16[2], fm16[2];
    #pragma unroll
    for (int c = 0; c < 2; ++c) {
        float4 bx = boxes[c * NT + tid];
        int y1 = max(0, (int)(bx.x * (float)HH));   // trunc == astype(int32)
        int x1 = max(0, (int)(bx.y * (float)WW));
        int y2 = min(HH, (int)(bx.z * (float)HH));
        int x2 = min(WW, (int)(bx.w * (float)WW));
        coordS[c * NT + tid] = make_uint2(((unsigned)y1 << 16) | (unsigned)x1,
                                          ((unsigned)y2 << 16) | (unsigned)x2);
        bool valid = (y1 < y2) && (x1 < x2);
        bool yint  = valid && (y1 < tileY + BANDH) && (y2 > tileY);
        bool yfull = valid && (y1 <= tileY) && (y2 >= tileY + BANDH);
        // strips intersected in x: [x1>>7, ceil(x2/128))
        int ilo = x1 >> 7, ihi = min(NSTRIP, (x2 + SW - 1) >> 7);
        unsigned imask = 0;
        if (yint && ihi > ilo) imask = (unsigned)(((1u << (ihi - ilo)) - 1u) << ilo);
        // strips fully covered in x: [ceil(x1/128), x2>>7)
        int clo = (x1 + SW - 1) >> 7, chi = x2 >> 7;
        unsigned cmask = 0;
        if (yfull && chi > clo) cmask = (unsigned)(((1u << (chi - clo)) - 1u) << clo);
        im16[c] = imask; fm16[c] = cmask;
    }
    #pragma unroll
    for (int c = 0; c < 2; ++c)
        #pragma unroll
        for (int s = 0; s < NSTRIP; ++s) {
            unsigned long long bi = __ballot((im16[c] >> s) & 1);
            unsigned long long bf = __ballot((fm16[c] >> s) & 1);
            if (lane == 0) { imS[s][c][wid] = bi; fmS[s][c][wid] = bf; }
        }
    __syncthreads();  // coordS + ballots visible

    // ---- 16 leader lanes: per-strip lastFull + pruned compaction ----
    if (tid < NSTRIP) {
        const int s = tid;
        int lf = -1;
        for (int c = 1; c >= 0 && lf < 0; --c)
            for (int w = 7; w >= 0 && lf < 0; --w) {
                unsigned long long m = fmS[s][c][w];
                if (m) lf = c * 512 + w * 64 + 63 - __clzll(m);
            }
        lastFullS[s] = lf;
        int j = 0;
        for (int c = 0; c < 2; ++c)
            for (int w = 0; w < 8; ++w) {
                unsigned long long m = imS[s][c][w];
                int base = c * 512 + w * 64;
                int d = lf - base;
                if (d >= 63) m = 0;
                else if (d >= 0) m &= (~0ull) << (d + 1);
                while (m) {
                    int b = base + __builtin_ctzll(m);
                    m &= m - 1;
                    if (j < CAP) { clistS[s][j] = coordS[b]; cidxS[s][j] = (short)b; }
                    ++j;
                }
            }
        cntS[s] = (j <= CAP) ? j : -1;
    }
    __syncthreads();  // lists ready

    // ---- phase A: per-pixel ownership, registers only ----
    const int py = tileY + wid;          // this wave's image row
    const int lx = lane << 2;            // 0..252, 4 px per lane
    int fnd[8][4];
    bool uni[8];
    #pragma unroll
    for (int xi = 0; xi < 8; ++xi) {
        const int s   = xi * 2 + (lane >> 5);
        const int px0 = xi * 256 + lx;
        const int lf  = lastFullS[s];
        int f0 = lf, f1 = lf, f2 = lf, f3 = lf;
        const int c = cntS[s];
        if (c >= 0) {
            for (int j = 0; j < c; ++j) {
                uint2 pc = clistS[s][j];
                int bidx = cidxS[s][j];
                int by1 = (int)(pc.x >> 16), bx1 = (int)(pc.x & 0xffffu);
                int by2 = (int)(pc.y >> 16), bx2 = (int)(pc.y & 0xffffu);
                if (py >= by1 && py < by2) {
                    if (px0     >= bx1 && px0     < bx2) f0 = bidx;
                    if (px0 + 1 >= bx1 && px0 + 1 < bx2) f1 = bidx;
                    if (px0 + 2 >= bx1 && px0 + 2 < bx2) f2 = bidx;
                    if (px0 + 3 >= bx1 && px0 + 3 < bx2) f3 = bidx;
                }
            }
        } else {
            // overflow fallback (astronomically rare, kept for correctness)
            for (int b = lf + 1; b < NB; ++b) {
                uint2 pc = coordS[b];
                int by1 = (int)(pc.x >> 16), bx1 = (int)(pc.x & 0xffffu);
                int by2 = (int)(pc.y >> 16), bx2 = (int)(pc.y & 0xffffu);
                if (py >= by1 && py < by2) {
                    if (px0     >= bx1 && px0     < bx2) f0 = b;
                    if (px0 + 1 >= bx1 && px0 + 1 < bx2) f1 = b;
                    if (px0 + 2 >= bx1 && px0 + 2 < bx2) f2 = b;
                    if (px0 + 3 >= bx1 && px0 + 3 < bx2) f3 = b;
                }
            }
        }
        fnd[xi][0] = f0; fnd[xi][1] = f1; fnd[xi][2] = f2; fnd[xi][3] = f3;
        uni[xi] = (f0 == f1) && (f1 == f2) && (f2 == f3);
    }

    // ---- phase B: channel-outer stores -> 5 sequential 8KB runs per wave ----
    const float* bfp = (const float*)boxes;
    #pragma unroll
    for (int ch = 0; ch < 5; ++ch) {
        float* op = out + (size_t)ch * ((size_t)HH * WW) + (size_t)py * WW;
        #pragma unroll
        for (int xi = 0; xi < 8; ++xi) {
            float4 v;
            if (uni[xi]) {
                int f = fnd[xi][0];
                float val;
                if (ch == 0) val = (f >= 0) ? 1.f : 0.f;
                else         val = (f >= 0) ? bfp[f * 4 + (ch - 1)] : 0.f;
                v = make_float4(val, val, val, val);
            } else {
                #pragma unroll
                for (int k = 0; k < 4; ++k) {
                    int f = fnd[xi][k];
                    float val;
                    if (ch == 0) val = (f >= 0) ? 1.f : 0.f;
                    else         val = (f >= 0) ? bfp[f * 4 + (ch - 1)] : 0.f;
                    ((float*)&v)[k] = val;
                }
            }
            *(float4*)(op + xi * 256 + lx) = v;
        }
    }
}

extern "C" void kernel_launch(void* const* d_in, const int* in_sizes, int n_in,
                              void* d_out, int out_size, void* d_ws, size_t ws_size,
                              hipStream_t stream) {
    const float4* boxes = (const float4*)d_in[0];
    float* out = (float*)d_out;
    dim3 grid(HH / BANDH);  // 256 blocks = 1 per CU
    dim3 block(NT);
    paint_kernel<<<grid, block, 0, stream>>>(boxes, out);
}

// Round 4
// 94.096 us; speedup vs baseline: 1.1313x; 1.0856x over previous
//
#include <hip/hip_runtime.h>

#define HH 2048
#define WW 2048
#define NB 1024
#define TW 128  // tile width
#define TH 32   // tile height
// R0 structure (best so far), single change: all output stores are
// NONTEMPORAL (bypass L2 write-allocate), via a native ext_vector float4
// (clang builtin rejects HIP_vector_type). 84MB streaming write churns the
// 4MiB/XCD L2 with dirty lines; fillBufferAligned hits 6.2 TB/s on this
// same buffer via the streaming-store path. nt stores test that theory.

typedef float f32x4 __attribute__((ext_vector_type(4)));

__device__ __forceinline__ void nt_store4(float* p, float a, float b, float c, float d) {
    f32x4 v = {a, b, c, d};
    __builtin_nontemporal_store(v, (f32x4*)p);
}

__global__ __launch_bounds__(256, 4) void paint_kernel(const float4* __restrict__ boxes,
                                                       float* __restrict__ out) {
    __shared__ unsigned long long imaskS[4][4];  // [chunk][wave]
    __shared__ unsigned long long fmaskS[4][4];
    __shared__ uint2 clist[NB];  // packed coords of pruned candidates (idx > lastFull)
    __shared__ short cidxS[NB];

    const int tid  = threadIdx.x;
    const int lane = tid & 63;
    const int wid  = tid >> 6;
    const int tileX = blockIdx.x * TW;
    const int tileY = blockIdx.y * TH;

    // ---- pass 1: load + convert + ballot; coords stay in registers ----
    int ry1[4], rx1[4], ry2[4], rx2[4];
    bool rint[4];
    #pragma unroll
    for (int c = 0; c < 4; ++c) {
        float4 bx = boxes[c * 256 + tid];
        int y1 = max(0, (int)(bx.x * (float)HH));   // trunc-toward-zero == astype(int32)
        int x1 = max(0, (int)(bx.y * (float)WW));
        int y2 = min(HH, (int)(bx.z * (float)HH));
        int x2 = min(WW, (int)(bx.w * (float)WW));
        ry1[c] = y1; rx1[c] = x1; ry2[c] = y2; rx2[c] = x2;
        bool valid = (y1 < y2) && (x1 < x2);
        bool inter = valid && (y1 < tileY + TH) && (y2 > tileY) &&
                     (x1 < tileX + TW) && (x2 > tileX);
        bool full  = (y1 <= tileY) && (y2 >= tileY + TH) &&
                     (x1 <= tileX) && (x2 >= tileX + TW);
        rint[c] = inter;
        unsigned long long mi = __ballot(inter);
        unsigned long long mf = __ballot(full);
        if (lane == 0) { imaskS[c][wid] = mi; fmaskS[c][wid] = mf; }
    }
    __syncthreads();  // barrier 1

    // ---- lastFull: highest-index box fully covering the tile (block-uniform) ----
    int lastFull = -1;
    #pragma unroll
    for (int c = 3; c >= 0; --c)
        #pragma unroll
        for (int w = 3; w >= 0; --w)
            if (lastFull < 0) {
                unsigned long long m = fmaskS[c][w];
                if (m) lastFull = c * 256 + w * 64 + 63 - __clzll(m);
            }

    // ---- prune masks to idx > lastFull; compute compaction offsets ----
    int cnt_all = 0;
    int myoff[4];
    #pragma unroll
    for (int c = 0; c < 4; ++c) {
        #pragma unroll
        for (int w = 0; w < 4; ++w) {
            unsigned long long m = imaskS[c][w];
            int d = lastFull - (c * 256 + w * 64);
            if (d >= 63) m = 0;
            else if (d >= 0) m &= (~0ull) << (d + 1);
            if (w == wid)
                myoff[c] = cnt_all + __popcll(m & ((1ull << lane) - 1ull));
            cnt_all += __popcll(m);
        }
    }

    // ---- sparse compaction writes (coords still in registers) ----
    #pragma unroll
    for (int c = 0; c < 4; ++c) {
        int b = c * 256 + tid;
        if (rint[c] && b > lastFull) {
            clist[myoff[c]] = make_uint2(((unsigned)ry1[c] << 16) | (unsigned)rx1[c],
                                         ((unsigned)ry2[c] << 16) | (unsigned)rx2[c]);
            cidxS[myoff[c]] = (short)b;
        }
    }
    __syncthreads();  // barrier 2

    const int qx  = tid & 31;
    const int px0 = tileX + qx * 4;
    const int ry  = tid >> 5;
    const int py0 = tileY + ry * 4;

    if (cnt_all == 0) {
        // ---- uniform fast path: whole tile = lastFull box (or zeros) ----
        float4 bv = make_float4(0.f, 0.f, 0.f, 0.f);
        float on = 0.f;
        if (lastFull >= 0) { bv = boxes[lastFull]; on = 1.f; }
        float vals[5] = {on, bv.x, bv.y, bv.z, bv.w};
        #pragma unroll
        for (int ch = 0; ch < 5; ++ch) {
            float val = vals[ch];
            size_t base = (size_t)ch * (HH * WW);
            #pragma unroll
            for (int s = 0; s < 4; ++s)
                nt_store4(out + base + (size_t)(py0 + s) * WW + px0, val, val, val, val);
        }
    } else {
        // ---- per-pixel ownership: ascending overwrite over tiny pruned list ----
        int fnd[4][4];
        #pragma unroll
        for (int s = 0; s < 4; ++s)
            #pragma unroll
            for (int k = 0; k < 4; ++k) fnd[s][k] = lastFull;
        for (int j = 0; j < cnt_all; ++j) {
            uint2 pc = clist[j];           // one ds_read_b64
            int bidx = cidxS[j];
            int by1 = (int)(pc.x >> 16), bx1 = (int)(pc.x & 0xffff);
            int by2 = (int)(pc.y >> 16), bx2 = (int)(pc.y & 0xffff);
            #pragma unroll
            for (int s = 0; s < 4; ++s) {
                int py = py0 + s;
                bool yin = (py >= by1) && (py < by2);
                #pragma unroll
                for (int k = 0; k < 4; ++k) {
                    int px = px0 + k;
                    if (yin && px >= bx1 && px < bx2) fnd[s][k] = bidx;
                }
            }
        }
        #pragma unroll
        for (int s = 0; s < 4; ++s) {
            float v[5][4];
            #pragma unroll
            for (int k = 0; k < 4; ++k) {
                int f = fnd[s][k];
                float4 bv = (f >= 0) ? boxes[f] : make_float4(0.f, 0.f, 0.f, 0.f);
                float on = (f >= 0) ? 1.f : 0.f;
                v[0][k] = on;
                v[1][k] = bv.x;
                v[2][k] = bv.y;
                v[3][k] = bv.z;
                v[4][k] = bv.w;
            }
            size_t pb = (size_t)(py0 + s) * WW + px0;
            #pragma unroll
            for (int ch = 0; ch < 5; ++ch)
                nt_store4(out + (size_t)ch * (HH * WW) + pb,
                          v[ch][0], v[ch][1], v[ch][2], v[ch][3]);
        }
    }
}

extern "C" void kernel_launch(void* const* d_in, const int* in_sizes, int n_in,
                              void* d_out, int out_size, void* d_ws, size_t ws_size,
                              hipStream_t stream) {
    const float4* boxes = (const float4*)d_in[0];
    float* out = (float*)d_out;
    dim3 grid(WW / TW, HH / TH);  // 16 x 64 = 1024 blocks
    dim3 block(256);
    paint_kernel<<<grid, block, 0, stream>>>(boxes, out);
}